// Round 8
// baseline (79.410 us; speedup 1.0000x reference)
//
#include <hip/hip_runtime.h>
#include <math.h>

// StructLoss: sqrt(mean(|grads4(outputs - labels)|) + 1e-16)
// grads4 linear -> compute on d = outputs - labels.
// [B=16, C=6, H=512, W=512] fp32; mean over B*4C*H*W.
//
// Persistent band + circular LDS row buffer + DMA/compute overlap:
// each block owns a 32-row band of one plane. LDS = 18-slot circular row
// buffer per array (slot = row mod 18). Per 8-row iteration: issue
// global_load_lds DMA for the NEXT 8 rows (fire-and-forget, no VGPR
// round-trip), compute current 8 rows from LDS, one barrier. DMA read-set
// (10 slots) and write-set (8 slots) are exactly disjoint mod 18.
// Each row staged once per block (halo 2/32). Boundary rows: clamped DMA
// source + 0/1 mask at consume. Fused last-block mean+sqrt tail.

#define NTHREADS 256
#define WV 512
#define HT 512
#define PLANES 96
#define BAND 32
#define TROWS 8
#define NIT (BAND / TROWS)                  // 4
#define SLOTS 18
#define BLOCKS_PER_PLANE (HT / BAND)        // 16
#define NBLOCKS (PLANES * BLOCKS_PER_PLANE) // 1536

__device__ __forceinline__ void gload_lds16(const float* g, float* l) {
    __builtin_amdgcn_global_load_lds(
        (const __attribute__((address_space(1))) void*)g,
        (__attribute__((address_space(3))) void*)l, 16, 0, 0);
}

struct Row { float d[8]; float eL, eR; };

__device__ __forceinline__ Row lds_row(const float* __restrict__ sd,
                                       int gr, int lane) {
    const int slot = (gr + 2 * SLOTS) % SLOTS;       // gr >= -1
    const float m = ((unsigned)gr < (unsigned)HT) ? 1.f : 0.f;  // zero-pad
    const float* po = sd + slot * WV + lane * 8;
    const float* pl = po + SLOTS * WV;
    const float4 a = *reinterpret_cast<const float4*>(po);
    const float4 b = *reinterpret_cast<const float4*>(po + 4);
    const float4 c = *reinterpret_cast<const float4*>(pl);
    const float4 d = *reinterpret_cast<const float4*>(pl + 4);
    Row row;
    row.d[0] = m * (a.x - c.x); row.d[1] = m * (a.y - c.y);
    row.d[2] = m * (a.z - c.z); row.d[3] = m * (a.w - c.w);
    row.d[4] = m * (b.x - d.x); row.d[5] = m * (b.y - d.y);
    row.d[6] = m * (b.z - d.z); row.d[7] = m * (b.w - d.w);
    const float up = __shfl_up(row.d[7], 1, 64);
    const float dn = __shfl_down(row.d[0], 1, 64);
    row.eL = (lane == 0)  ? 0.f : up;    // col 8l-1 (image zero-pad)
    row.eR = (lane == 63) ? 0.f : dn;    // col 8l+8 (image zero-pad)
    return row;
}

__device__ __forceinline__ float stencil(const Row& rp, const Row& rc,
                                         const Row& rn) {
    float a = 0.f;
    #pragma unroll
    for (int k = 0; k < 8; ++k) {
        const float cL = (k > 0) ? rc.d[k - 1] : rc.eL;
        const float cR = (k < 7) ? rc.d[k + 1] : rc.eR;
        const float pL = (k > 0) ? rp.d[k - 1] : rp.eL;
        const float pR = (k < 7) ? rp.d[k + 1] : rp.eR;
        const float nL = (k > 0) ? rn.d[k - 1] : rn.eL;
        const float nR = (k < 7) ? rn.d[k + 1] : rn.eR;

        const float gy = rp.d[k] - rn.d[k];   // x[i-1,j]   - x[i+1,j]
        const float gx = cL - cR;             // x[i,j-1]   - x[i,j+1]
        const float gD = pL - nR;             // x[i-1,j-1] - x[i+1,j+1]
        const float gd = pR - nL;             // x[i-1,j+1] - x[i+1,j-1]
        a += fabsf(gy) + fabsf(gx) + fabsf(gD) + fabsf(gd);
    }
    return a;
}

__global__ __launch_bounds__(NTHREADS) void struct_loss(
        const float* __restrict__ out_p, const float* __restrict__ lab_p,
        float* __restrict__ partials, unsigned* __restrict__ counter,
        float* __restrict__ out, double inv_count) {
    __shared__ float sd[2 * SLOTS * WV];             // 73,728 B -> 2 blocks/CU

    const int tid  = threadIdx.x;
    const int wid  = tid >> 6;
    const int lane = tid & 63;
    const int plane = blockIdx.x >> 4;               // / BLOCKS_PER_PLANE
    const int R0    = (blockIdx.x & 15) * BAND;
    const size_t pbase = (size_t)plane * (HT * WV);

    // ---- prologue: stage rows R0-1 .. R0+8 (10 rows, 40 chunks, 10/wave) --
    #pragma unroll
    for (int k = 0; k < 10; ++k) {
        const int c    = wid * 10 + k;               // 0..39
        const int arr  = c / 20;
        const int rest = c % 20;
        const int j = rest >> 1, h = rest & 1;
        const int gr   = R0 - 1 + j;
        const int slot = (gr + 2 * SLOTS) % SLOTS;
        const int grc  = min(max(gr, 0), HT - 1);    // clamp: addr always valid
        const float* src = (arr ? lab_p : out_p) + pbase
                         + (size_t)grc * WV + h * 256 + lane * 4;
        gload_lds16(src, sd + arr * (SLOTS * WV) + slot * WV + h * 256);
    }
    __syncthreads();

    float acc = 0.f;

    #pragma unroll
    for (int t = 0; t < NIT; ++t) {
        const int r0 = R0 + t * TROWS;

        // Issue DMA for rows r0+9 .. r0+16 BEFORE compute (hides under it).
        if (t < NIT - 1) {
            #pragma unroll
            for (int k = 0; k < 8; ++k) {
                const int c    = wid * 8 + k;        // 0..31
                const int arr  = c >> 4;
                const int rest = c & 15;
                const int j = rest >> 1, h = rest & 1;
                const int gr   = r0 + 9 + j;
                const int slot = gr % SLOTS;
                const int grc  = min(gr, HT - 1);
                const float* src = (arr ? lab_p : out_p) + pbase
                                 + (size_t)grc * WV + h * 256 + lane * 4;
                gload_lds16(src, sd + arr * (SLOTS * WV) + slot * WV + h * 256);
            }
        }

        // Compute rows r0+2*wid, r0+2*wid+1 from LDS (slots r0-1..r0+8).
        const int rw = r0 + 2 * wid;
        Row rp = lds_row(sd, rw - 1, lane);
        Row rc = lds_row(sd, rw,     lane);
        Row rn = lds_row(sd, rw + 1, lane);
        acc += stencil(rp, rc, rn);
        Row rn2 = lds_row(sd, rw + 2, lane);
        acc += stencil(rc, rn, rn2);

        __syncthreads();   // DMA landed (vmcnt drain) + all reads done before
                           // next iteration's DMA overwrites old slots
    }

    // ---- wave + block reduction ----
    #pragma unroll
    for (int off = 32; off > 0; off >>= 1)
        acc += __shfl_down(acc, off, 64);

    __shared__ float smem[NTHREADS / 64];
    if (lane == 0) smem[wid] = acc;
    __syncthreads();

    __shared__ bool amLast;
    if (tid == 0) {
        float s = 0.f;
        #pragma unroll
        for (int w = 0; w < NTHREADS / 64; ++w) s += smem[w];
        partials[blockIdx.x] = s;
        __threadfence();                            // publish partial
        const unsigned old = atomicAdd(counter, 1u);
        amLast = (old == (unsigned)(NBLOCKS - 1));
    }
    __syncthreads();

    if (amLast) {
        __threadfence();                            // see all partials
        double s = 0.0;
        for (int i = tid; i < NBLOCKS; i += NTHREADS)  // fixed order: determ.
            s += (double)partials[i];
        #pragma unroll
        for (int off = 32; off > 0; off >>= 1)
            s += __shfl_down(s, off, 64);
        __shared__ double dsm[NTHREADS / 64];
        if (lane == 0) dsm[wid] = s;
        __syncthreads();
        if (tid == 0) {
            double tt = 0.0;
            #pragma unroll
            for (int w = 0; w < NTHREADS / 64; ++w) tt += dsm[w];
            out[0] = (float)sqrt(tt * inv_count + 1e-16);
        }
    }
}

extern "C" void kernel_launch(void* const* d_in, const int* in_sizes, int n_in,
                              void* d_out, int out_size, void* d_ws, size_t ws_size,
                              hipStream_t stream) {
    const float* outputs = (const float*)d_in[0];
    const float* labels  = (const float*)d_in[1];
    float* out = (float*)d_out;

    unsigned* counter = (unsigned*)d_ws;            // u32 at offset 0
    float* partials   = (float*)d_ws + 16;          // 1536 floats at 64 B off

    const double inv_count = 1.0 / (16.0 * 24.0 * 512.0 * 512.0);

    hipMemsetAsync(counter, 0, sizeof(unsigned), stream);
    struct_loss<<<NBLOCKS, NTHREADS, 0, stream>>>(outputs, labels, partials,
                                                  counter, out, inv_count);
}